// Round 14
// baseline (261.295 us; speedup 1.0000x reference)
//
#include <hip/hip_runtime.h>

#define N_TOK 21952          // 28*28*28
#define NR    343            // 7*7*7
#define ATT_SCALE 0.17677669529663687f   // 32^-0.5
#define LOG2E 1.44269504088896340736f

typedef unsigned short u16;
typedef short  v8s __attribute__((ext_vector_type(8)));
typedef float  v4f __attribute__((ext_vector_type(4)));

__device__ __forceinline__ float bf2f(unsigned u) {
    return __builtin_bit_cast(float, u << 16);
}
__device__ __forceinline__ u16 f2bf(float f) {
    unsigned u = __builtin_bit_cast(unsigned, f);
    u += 0x7fffu + ((u >> 16) & 1u);
    return (u16)(u >> 16);
}

// CK-pattern global->LDS DMA (16B/lane).  LDS dest = wave-uniform base +
// lane*16 (m104); on gfx950 the low 32 bits of a flat LDS pointer ARE the
// LDS byte offset.
__device__ __forceinline__ void gload_lds16(const u16* g, u16* l) {
    __builtin_amdgcn_global_load_lds(
        (const __attribute__((address_space(1))) unsigned*)g,
        (__attribute__((address_space(3))) unsigned*)(unsigned)(uintptr_t)l,
        16, 0, 0);
}

// ---------------------------------------------------------------------------
// x fp32 -> bf16 (xb).  8 elems / thread, exact grid.
// ---------------------------------------------------------------------------
__global__ __launch_bounds__(256) void convert_x_kernel(
    const float* __restrict__ x, u16* __restrict__ xb)
{
    size_t i = ((size_t)blockIdx.x * 256 + threadIdx.x) * 8;   // exact: N*256
    float4 a0 = *(const float4*)(x + i);
    float4 a1 = *(const float4*)(x + i + 4);
    uint4 av;
    av.x = (unsigned)f2bf(a0.x) | ((unsigned)f2bf(a0.y) << 16);
    av.y = (unsigned)f2bf(a0.z) | ((unsigned)f2bf(a0.w) << 16);
    av.z = (unsigned)f2bf(a1.x) | ((unsigned)f2bf(a1.y) << 16);
    av.w = (unsigned)f2bf(a1.z) | ((unsigned)f2bf(a1.w) << 16);
    *(uint4*)(xb + i) = av;
}

// ---------------------------------------------------------------------------
// Weight conversion fp32->bf16.  q weights pre-scaled by ATT_SCALE*LOG2E so
// attention can use native exp2.
// ---------------------------------------------------------------------------
#define WSEG0 16384   // lepe  (65536/4)
#define WSEG1 24576   // +q1   (32768/4)
#define WSEG2 32768   // +q2
#define WSEG3 49152   // +kv2  (65536/4)
#define WSEG4 65536   // +k1
#define WSEG5 81920   // +proj
#define WSEG6 82112   // +bias (768/4)

__global__ __launch_bounds__(256) void convert_w_kernel(
    const float* __restrict__ wl,  const float* __restrict__ wq1,
    const float* __restrict__ wq2, const float* __restrict__ wk2,
    const float* __restrict__ wk1, const float* __restrict__ wp,
    const float* __restrict__ lepe_b,
    u16* wb_comb, u16* wb_k1, u16* wb_p, float* bias_all)
{
    int gid = blockIdx.x * 256 + threadIdx.x;
    if (gid >= WSEG6) return;
    if (gid >= WSEG5) {                      // bias_all
        int b = gid - WSEG5;
        float4 v;
        int i = b * 4;
        v.x = (i + 0 < 256) ? lepe_b[i + 0] : 0.f;
        v.y = (i + 1 < 256) ? lepe_b[i + 1] : 0.f;
        v.z = (i + 2 < 256) ? lepe_b[i + 2] : 0.f;
        v.w = (i + 3 < 256) ? lepe_b[i + 3] : 0.f;
        *(float4*)(bias_all + i) = v;
        return;
    }
    const float* s; u16* d; int l; float sc = 1.f;
    if      (gid < WSEG0) { s = wl;  d = wb_comb;           l = gid; }
    else if (gid < WSEG1) { s = wq1; d = wb_comb + 65536;   l = gid - WSEG0; sc = ATT_SCALE * LOG2E; }
    else if (gid < WSEG2) { s = wq2; d = wb_comb + 98304;   l = gid - WSEG1; sc = ATT_SCALE * LOG2E; }
    else if (gid < WSEG3) { s = wk2; d = wb_comb + 131072;  l = gid - WSEG2; }
    else if (gid < WSEG4) { s = wk1; d = wb_k1;             l = gid - WSEG3; }
    else                  { s = wp;  d = wb_p;              l = gid - WSEG4; }
    float4 v = *(const float4*)(s + (size_t)l * 4);
    *(ushort4*)(d + (size_t)l * 4) =
        make_ushort4(f2bf(v.x * sc), f2bf(v.y * sc), f2bf(v.z * sc), f2bf(v.w * sc));
}

// ---------------------------------------------------------------------------
// sr_w [co][ci][tap] fp32 -> wsr_t [tap][co][ci] bf16.
// ---------------------------------------------------------------------------
__global__ __launch_bounds__(256) void convert_sr_kernel(
    const float* __restrict__ wsr, u16* __restrict__ wt)
{
    int u  = blockIdx.x * 256 + threadIdx.x;   // 65536 = 256 co x 256 ci
    int co = u >> 8, ci = u & 255;
    const float* src = wsr + (size_t)co * 16384 + ci * 64;
#pragma unroll
    for (int t4 = 0; t4 < 16; t4++) {
        float4 v = *(const float4*)(src + t4 * 4);
        int t = t4 * 4;
        wt[(size_t)(t + 0) * 65536 + co * 256 + ci] = f2bf(v.x);
        wt[(size_t)(t + 1) * 65536 + co * 256 + ci] = f2bf(v.y);
        wt[(size_t)(t + 2) * 65536 + co * 256 + ci] = f2bf(v.z);
        wt[(size_t)(t + 3) * 65536 + co * 256 + ci] = f2bf(v.w);
    }
}

// ---------------------------------------------------------------------------
// m97-structure K=256 GEMM with global_load_lds staging (width 16):
//   out[M,ldout] = A @ W^T [+ bias]
// BM=128 x BN=64, BK=32, single-buffered linear LDS.
// mode: 0 = bf16 out (+bias), 1 = fp32 out (+bias, scalar stores)
// ---------------------------------------------------------------------------
__global__ __launch_bounds__(256, 4) void gemm_lds(
    const u16* __restrict__ A, const u16* __restrict__ W,
    const float* __restrict__ bias, void* __restrict__ outp,
    int M, int ldout, int mode, int nwg, int NT)
{
    __shared__ u16 smbuf[128 * 64];            // 16 KB; K-loop uses 12 KB
    u16* Asm = smbuf;                          // [128][32]
    u16* Bsm = smbuf + 128 * 32;               // [64][32]
    const int tid = threadIdx.x;

    // bijective XCD swizzle (m204)
    int bid = blockIdx.x;
    int q = nwg >> 3, r8 = nwg & 7;
    int xcd = bid & 7, idx = bid >> 3;
    int wgid = (xcd < r8 ? xcd * (q + 1) : r8 * (q + 1) + (xcd - r8) * q) + idx;
    const int m0 = (wgid / NT) * 128;
    const int n0 = (wgid % NT) * 64;

    const int wave = tid >> 6, lane = tid & 63;
    const int wm = (wave & 1) * 64, wn = (wave >> 1) * 32;
    const int fr = lane & 15, fq = lane >> 4;

    const int l4 = lane >> 2, lc = (lane & 3) * 8;
    int ra0 = m0 + wave * 32 + l4;  if (ra0 >= M) ra0 = M - 1;
    int ra1 = ra0 + 16;             if (ra1 >= M) ra1 = M - 1;
    const u16* gA0 = A + (size_t)ra0 * 256 + lc;
    const u16* gA1 = A + (size_t)ra1 * 256 + lc;
    const u16* gB  = W + (size_t)(n0 + wave * 16 + l4) * 256 + lc;
    u16* ldsA0 = Asm + (wave * 32) * 32;
    u16* ldsA1 = Asm + (wave * 32 + 16) * 32;
    u16* ldsB  = Bsm + (wave * 16) * 32;

    v4f acc[4][2];
#pragma unroll
    for (int i = 0; i < 4; i++)
#pragma unroll
        for (int j = 0; j < 2; j++) acc[i][j] = (v4f){0.f, 0.f, 0.f, 0.f};

    for (int kk = 0; kk < 256; kk += 32) {
        gload_lds16(gA0 + kk, ldsA0);
        gload_lds16(gA1 + kk, ldsA1);
        gload_lds16(gB  + kk, ldsB);
        __syncthreads();

        v8s af[4], bf[2];
#pragma unroll
        for (int i = 0; i < 4; i++)
            af[i] = *(const v8s*)(Asm + (wm + i * 16 + fr) * 32 + fq * 8);
#pragma unroll
        for (int j = 0; j < 2; j++)
            bf[j] = *(const v8s*)(Bsm + (wn + j * 16 + fr) * 32 + fq * 8);
#pragma unroll
        for (int i = 0; i < 4; i++)
#pragma unroll
            for (int j = 0; j < 2; j++)
                acc[i][j] = __builtin_amdgcn_mfma_f32_16x16x32_bf16(
                    af[i], bf[j], acc[i][j], 0, 0, 0);
        __syncthreads();
    }

    if (mode == 0) {
#pragma unroll
        for (int i = 0; i < 4; i++)
#pragma unroll
            for (int j = 0; j < 2; j++) {
                int col = wn + j * 16 + fr;
#pragma unroll
                for (int rr = 0; rr < 4; rr++) {
                    int row = wm + i * 16 + fq * 4 + rr;
                    float v = acc[i][j][rr];
                    if (bias) v += bias[n0 + col];
                    smbuf[row * 64 + col] = f2bf(v);
                }
            }
        __syncthreads();
#pragma unroll
        for (int i = 0; i < 4; i++) {
            int u = tid + i * 256;              // 0..1023
            int row = u >> 3, seg = (u & 7) * 8;
            if (m0 + row < M) {
                uint4 a = *(const uint4*)(smbuf + row * 64 + seg);
                *(uint4*)((u16*)outp + (size_t)(m0 + row) * ldout + n0 + seg) = a;
            }
        }
    } else {
        float* outf = (float*)outp;
#pragma unroll
        for (int i = 0; i < 4; i++)
#pragma unroll
            for (int j = 0; j < 2; j++) {
                int col = n0 + wn + j * 16 + fr;
#pragma unroll
                for (int rr = 0; rr < 4; rr++) {
                    int row = m0 + wm + i * 16 + fq * 4 + rr;
                    if (row >= M) continue;
                    float v = acc[i][j][rr];
                    if (bias) v += bias[col];
                    outf[(size_t)row * ldout + col] = v;
                }
            }
    }
}

// ---------------------------------------------------------------------------
// SR conv as tap-split GEMM, LOAD-early/WRITE-late double-buffered.
// ---------------------------------------------------------------------------
#define LDA 40   // padded LDS row stride (bf16 elems)

__global__ __launch_bounds__(256) void sr_gemm(
    const u16* __restrict__ xb, const u16* __restrict__ Wt,
    float* __restrict__ partials)
{
    __shared__ u16 Asm[2][128 * LDA];
    __shared__ u16 Bsm[2][64 * LDA];
    const int tid = threadIdx.x;
    const int m0 = blockIdx.x * 128;   // p tile
    const int n0 = blockIdx.y * 64;    // co tile
    const int z  = blockIdx.z;         // taps 2z, 2z+1
    const int wave = tid >> 6, lane = tid & 63;
    const int wm = (wave & 1) * 64, wn = (wave >> 1) * 32;
    const int fr = lane & 15, fq = lane >> 4;

    const int r0 = tid >> 2;
    const int r1 = r0 + 64;
    const int seg = (tid & 3) * 8;
    const int p0 = m0 + r0, p1 = m0 + r1;
    const int pz0 = p0 / 49, pr0 = p0 % 49, py0 = pr0 / 7, px0 = pr0 % 7;
    const int pz1 = p1 / 49, pr1 = p1 % 49, py1 = pr1 / 7, px1 = pr1 % 7;
    const int nb0 = pz0 * 4 * 784 + py0 * 4 * 28 + px0 * 4;
    const int nb1 = pz1 * 4 * 784 + py1 * 4 * 28 + px1 * 4;

    uint4 rv0, rv1, rbv;
    const uint4 Z = make_uint4(0, 0, 0, 0);

    auto G_LOAD = [&](int it) {
        int tap = z * 2 + (it >> 3);
        int ci0 = (it & 7) * 32;
        int kz = tap >> 4, ky = (tap >> 2) & 3, kx = tap & 3;
        int koff = kz * 784 + ky * 28 + kx;
        rv0 = (p0 < NR) ? *(const uint4*)(xb + (size_t)(nb0 + koff) * 256 + ci0 + seg) : Z;
        rv1 = (p1 < NR) ? *(const uint4*)(xb + (size_t)(nb1 + koff) * 256 + ci0 + seg) : Z;
        rbv = *(const uint4*)(Wt + (size_t)tap * 65536 + (size_t)(n0 + r0) * 256 + ci0 + seg);
    };
    auto L_WRITE = [&](int buf) {
        *(uint4*)(Asm[buf] + r0 * LDA + seg) = rv0;
        *(uint4*)(Asm[buf] + r1 * LDA + seg) = rv1;
        *(uint4*)(Bsm[buf] + r0 * LDA + seg) = rbv;
    };

    v4f acc[4][2];
#pragma unroll
    for (int i = 0; i < 4; i++)
#pragma unroll
        for (int j = 0; j < 2; j++) acc[i][j] = (v4f){0.f, 0.f, 0.f, 0.f};

    G_LOAD(0);
    L_WRITE(0);
    __syncthreads();

    int cur = 0;
    for (int it = 0; it < 16; it++) {
        if (it + 1 < 16) G_LOAD(it + 1);
        {
            v8s af[4], bfr[2];
#pragma unroll
            for (int i = 0; i < 4; i++)
                af[i] = *(const v8s*)(Asm[cur] + (wm + i * 16 + fr) * LDA + fq * 8);
#pragma unroll
            for (int j = 0; j < 2; j++)
                bfr[j] = *(const v8s*)(Bsm[cur] + (wn + j * 16 + fr) * LDA + fq * 8);
#pragma unroll
            for (int i = 0; i < 4; i++)
#pragma unroll
                for (int j = 0; j < 2; j++)
                    acc[i][j] = __builtin_amdgcn_mfma_f32_16x16x32_bf16(
                        af[i], bfr[j], acc[i][j], 0, 0, 0);
        }
        if (it + 1 < 16) L_WRITE(cur ^ 1);
        __syncthreads();
        cur ^= 1;
    }

    float* dst = partials + (size_t)z * (NR * 256);
#pragma unroll
    for (int i = 0; i < 4; i++) {
#pragma unroll
        for (int j = 0; j < 2; j++) {
            int col = n0 + wn + j * 16 + fr;
#pragma unroll
            for (int r = 0; r < 4; r++) {
                int row = m0 + wm + i * 16 + fq * 4 + r;
                if (row < NR) dst[(size_t)row * 256 + col] = acc[i][j][r];
            }
        }
    }
}

// ---------------------------------------------------------------------------
// Reduce 32 partials + sr bias, LayerNorm (C=256) + exact GELU -> bf16.
// ---------------------------------------------------------------------------
__global__ __launch_bounds__(256) void ln_gelu_kernel(
    const float* __restrict__ partials, const float* __restrict__ srb,
    const float* __restrict__ g, const float* __restrict__ b,
    u16* __restrict__ out)
{
    int row = blockIdx.x, c = threadIdx.x;
    float v = srb[c];
#pragma unroll
    for (int s = 0; s < 32; s++)
        v += partials[(size_t)s * (NR * 256) + row * 256 + c];
    float s1 = v, s2 = v * v;
#pragma unroll
    for (int off = 1; off < 64; off <<= 1) {
        s1 += __shfl_xor(s1, off);
        s2 += __shfl_xor(s2, off);
    }
    __shared__ float ws[4], ws2[4];
    int wave = c >> 6, lane = c & 63;
    if (lane == 0) { ws[wave] = s1; ws2[wave] = s2; }
    __syncthreads();
    float mean = (ws[0] + ws[1] + ws[2] + ws[3]) * (1.f / 256.f);
    float m2   = (ws2[0] + ws2[1] + ws2[2] + ws2[3]) * (1.f / 256.f);
    float var  = m2 - mean * mean;
    float xn = (v - mean) * rsqrtf(var + 1e-5f) * g[c] + b[c];
    out[row * 256 + c] = f2bf(0.5f * xn * (1.f + erff(xn * 0.70710678118654752f)));
}

// ---------------------------------------------------------------------------
// Depthwise 3x3x3 SAME conv, LDS-tiled.  y = xall cols 0..255 (row stride 768).
// ---------------------------------------------------------------------------
__global__ __launch_bounds__(256) void dwconv_kernel(
    const u16* __restrict__ xall, const float* __restrict__ w,
    const float* __restrict__ bias, u16* __restrict__ out)
{
    __shared__ float sm[216 * 64];
    __shared__ float sw[64 * 27];
    const int tid = threadIdx.x;
    const int t  = blockIdx.x;
    const int g  = blockIdx.y;
    const int tz = t / 49, tr = t % 49, ty = tr / 7, tx = tr % 7;

    for (int u = tid; u < 64 * 27; u += 256) sw[u] = w[g * 64 * 27 + u];

    for (int u = tid; u < 216 * 8; u += 256) {
        int r = u >> 3, c8 = (u & 7) * 8;
        int vz = tz * 4 - 1 + r / 36;
        int rem = r % 36;
        int vy = ty * 4 - 1 + rem / 6;
        int vx = tx * 4 - 1 + rem % 6;
        float f[8];
        if ((unsigned)vz < 28u && (unsigned)vy < 28u && (unsigned)vx < 28u) {
            int n = vz * 784 + vy * 28 + vx;
            uint4 raw = *(const uint4*)(xall + (size_t)n * 768 + g * 64 + c8);
            f[0] = bf2f(raw.x & 0xffffu); f[1] = bf2f(raw.x >> 16);
            f[2] = bf2f(raw.y & 0xffffu); f[3] = bf2f(raw.y >> 16);
            f[4] = bf2f(raw.z & 0xffffu); f[5] = bf2f(raw.z >> 16);
            f[6] = bf2f(raw.w & 0xffffu); f[7] = bf2f(raw.w >> 16);
        } else {
#pragma unroll
            for (int i = 0; i < 8; i++) f[i] = 0.f;
        }
        float* dst = &sm[r * 64 + c8];
        *(float4*)dst       = make_float4(f[0], f[1], f[2], f[3]);
        *(float4*)(dst + 4) = make_float4(f[4], f[5], f[6], f[7]);
    }
    __syncthreads();

    const int c  = tid & 63;
    const int ch = g * 64 + c;
    float wreg[27];
#pragma unroll
    for (int j = 0; j < 27; j++) wreg[j] = sw[c * 27 + j];
    const float bc = bias[ch];

    const int vbase = (tid >> 6) * 16;
    for (int v = vbase; v < vbase + 16; v++) {
        int vz = v >> 4, vy = (v >> 2) & 3, vx = v & 3;
        float a = bc;
#pragma unroll
        for (int dz = 0; dz < 3; dz++)
#pragma unroll
            for (int dy = 0; dy < 3; dy++)
#pragma unroll
                for (int dx = 0; dx < 3; dx++)
                    a = fmaf(sm[((vz + dz) * 36 + (vy + dy) * 6 + (vx + dx)) * 64 + c],
                             wreg[dz * 9 + dy * 3 + dx], a);
        int n = (tz * 4 + vz) * 784 + (ty * 4 + vy) * 28 + (tx * 4 + vx);
        out[(size_t)n * 256 + ch] = f2bf(a);
    }
}

// ===========================================================================
// Unified MFMA attention + fused "+lepe" epilogue.
// r11/r13 base (KP=40/VTP=360/PP=40, native exp2, 1016 blocks, setprio).
// ROUND 14: PV loop P double-buffer.  Old chain per kt was
//   8 ds_write -> lgkmcnt(0) full drain -> 3 ds_read -> 2 MFMA  (all serial).
// Now: {drain buf[cur] (writes issued LAST iter, covered by 2 MFMAs) ->
//   read P/V -> write buf[nxt] -> MFMA (compiler's counted lgkm tolerates
//   the 8 in-flight writes; in-order LDS completion)}.  +5 KB LDS
//   (61.4 KB, still 2 blocks/CU).
// ===========================================================================
#define KP  40    // K LDS row stride (bf16)
#define VTP 360   // V^T LDS row stride (bf16)
#define PP  40    // P LDS row stride (bf16)

__global__ __launch_bounds__(256) void attn_kernel(
    const u16* __restrict__ xall, const u16* __restrict__ kv1,
    const u16* __restrict__ lepe, u16* __restrict__ o)
{
    __shared__ u16 Ks[352 * KP];
    __shared__ u16 VTs[32 * VTP];
    __shared__ u16 Ps[4 * 2 * 16 * PP];      // 2 P buffers per wave
    const int tid = threadIdx.x;
    const int bx = blockIdx.x;         // 0..126  (window / q-tile id)
    const int h  = blockIdx.y;         // head
    const int mt0 = blockIdx.z * 11;   // m-tile half
    const bool br1 = bx < 63;
    const int qbase = bx * 352;                    // branch-1 only
    const int wi = bx - 63;                        // branch-2 only
    const int zb = (wi >> 4) & 3, yb = (wi >> 2) & 3, xw = wi & 3;
    const int wave = tid >> 6, lane = tid & 63;
    const int fr = lane & 15, fq = lane >> 4;

    for (int u = tid; u < 352 * 4; u += 256) {
        int r = u >> 2, seg = u & 3;
        uint4 kq = make_uint4(0, 0, 0, 0), vq = make_uint4(0, 0, 0, 0);
        if (r < NR) {
            const u16* kb;
            if (br1) {
                kb = kv1 + (size_t)r * 256 + h * 32;
            } else {
                int mz = r / 49, mr = r % 49, my = mr / 7, mx = mr % 7;
                int nk = (zb * 7 + mz) * 784 + (yb * 7 + my) * 28 + (xw * 7 + mx);
                kb = xall + (size_t)nk * 768 + 512 + h * 32;
            }
            kq = *(const uint4*)(kb + seg * 8);
            vq = *(const uint4*)(kb + 128 + seg * 8);
        }
        *(uint4*)(Ks + r * KP + seg * 8) = kq;
        int d0 = seg * 8;
        VTs[(d0 + 0) * VTP + r] = (u16)(vq.x & 0xffffu);
        VTs[(d0 + 1) * VTP + r] = (u16)(vq.x >> 16);
        VTs[(d0 + 2) * VTP + r] = (u16)(vq.y & 0xffffu);
        VTs[(d0 + 3) * VTP + r] = (u16)(vq.y >> 16);
        VTs[(d0 + 4) * VTP + r] = (u16)(vq.z & 0xffffu);
        VTs[(d0 + 5) * VTP + r] = (u16)(vq.z >> 16);
        VTs[(d0 + 6) * VTP + r] = (u16)(vq.w & 0xffffu);
        VTs[(d0 + 7) * VTP + r] = (u16)(vq.w >> 16);
    }
    __syncthreads();

    auto load_aq = [&](int mt) -> v8s {
        v8s a = {0, 0, 0, 0, 0, 0, 0, 0};
        if (br1) {
            int qrow = qbase + mt * 16 + fr;
            if (qrow < N_TOK)
                a = *(const v8s*)(xall + (size_t)qrow * 768 + 256 + h * 32 + fq * 8);
        } else {
            int tw = mt * 16 + fr;
            if (tw < NR) {
                int wz = tw / 49, tr2 = tw % 49, wy = tr2 / 7, wx = tr2 % 7;
                int nq = (zb * 7 + wz) * 784 + (yb * 7 + wy) * 28 + (xw * 7 + wx);
                a = *(const v8s*)(xall + (size_t)nq * 768 + 384 + h * 32 + fq * 8);
            }
        }
        return a;
    };

    u16* Pw0 = Ps + wave * 2 * 16 * PP;
    u16* Pw1 = Pw0 + 16 * PP;
    v8s aq = load_aq(mt0 + wave);
    for (int mt = mt0 + wave; mt < mt0 + 11; mt += 4) {
        v4f s[22];
        __builtin_amdgcn_s_setprio(1);
#pragma unroll
        for (int t = 0; t < 22; t++) {
            v8s bk = *(const v8s*)(Ks + (t * 16 + fr) * KP + fq * 8);
            s[t] = __builtin_amdgcn_mfma_f32_16x16x32_bf16(
                aq, bk, (v4f){0.f, 0.f, 0.f, 0.f}, 0, 0, 0);
        }
        __builtin_amdgcn_s_setprio(0);
        // prefetch next m-tile's q fragment: latency hides under softmax+PV
        v8s aqn = {0, 0, 0, 0, 0, 0, 0, 0};
        if (mt + 4 < mt0 + 11) aqn = load_aq(mt + 4);

        if (fr >= 7) {
#pragma unroll
            for (int r = 0; r < 4; r++) s[21][r] = -1e30f;
        }

        float inv_l[4];
#pragma unroll
        for (int r = 0; r < 4; r++) {
            // tree max (depth ~5)
            float a[11];
#pragma unroll
            for (int t = 0; t < 11; t++) a[t] = fmaxf(s[2 * t][r], s[2 * t + 1][r]);
#pragma unroll
            for (int t = 0; t < 5; t++) a[t] = fmaxf(a[t], a[t + 5]);
            float m = fmaxf(fmaxf(fmaxf(a[0], a[1]), fmaxf(a[2], a[3])),
                            fmaxf(a[4], a[10]));
#pragma unroll
            for (int off = 1; off < 16; off <<= 1) m = fmaxf(m, __shfl_xor(m, off));
            // native exp2 (scores pre-scaled by log2e) + tree sum
#pragma unroll
            for (int t = 0; t < 22; t++) {
                v4f sv = s[t];
                sv[r] = __builtin_amdgcn_exp2f(sv[r] - m);
                s[t] = sv;
            }
            float e[11];
#pragma unroll
            for (int t = 0; t < 11; t++) e[t] = s[t][r] + s[t + 11][r];
#pragma unroll
            for (int t = 0; t < 5; t++) e[t] += e[t + 6];
            float l = ((e[0] + e[1]) + (e[2] + e[3])) + (e[4] + e[5]);
#pragma unroll
            for (int off = 1; off < 16; off <<= 1) l += __shfl_xor(l, off);
            inv_l[r] = 1.f / l;
        }

        // --- PV with double-buffered P ---
        // prologue: stage kt=0 into buf0
#pragma unroll
        for (int tt = 0; tt < 2; tt++)
#pragma unroll
            for (int r = 0; r < 4; r++)
                Pw0[(fq * 4 + r) * PP + tt * 16 + fr] = f2bf(s[tt][r]);

        v4f o0 = {0.f, 0.f, 0.f, 0.f}, o1 = {0.f, 0.f, 0.f, 0.f};
#pragma unroll
        for (int kt = 0; kt < 11; kt++) {
            u16* curb = (kt & 1) ? Pw1 : Pw0;
            u16* nxtb = (kt & 1) ? Pw0 : Pw1;
            // drain: covers buf[cur] writes issued LAST iteration (or prologue)
            __asm__ volatile("s_waitcnt lgkmcnt(0)" ::: "memory");
            v8s ap  = *(const v8s*)(curb + fr * PP + fq * 8);
            v8s bv0 = *(const v8s*)(VTs + fr * VTP + kt * 32 + fq * 8);
            v8s bv1 = *(const v8s*)(VTs + (16 + fr) * VTP + kt * 32 + fq * 8);
            // issue next tile's P writes AFTER the reads (in-order LDS:
            // reads complete first, so MFMA's counted wait is satisfied
            // with these 8 writes still in flight)
            if (kt + 1 < 11) {
#pragma unroll
                for (int tt = 0; tt < 2; tt++) {
                    int t = (kt + 1) * 2 + tt;
#pragma unroll
                    for (int r = 0; r < 4; r++)
                        nxtb[(fq * 4 + r) * PP + tt * 16 + fr] = f2bf(s[t][r]);
                }
            }
            __builtin_amdgcn_s_setprio(1);
            o0 = __builtin_amdgcn_mfma_f32_16x16x32_bf16(ap, bv0, o0, 0, 0, 0);
            o1 = __builtin_amdgcn_mfma_f32_16x16x32_bf16(ap, bv1, o1, 0, 0, 0);
            __builtin_amdgcn_s_setprio(0);
        }

#pragma unroll
        for (int r = 0; r < 4; r++) {
            int rloc = mt * 16 + fq * 4 + r;
            size_t noff = 0; bool ok = false;
            if (br1) {
                int n = qbase + rloc;
                if (n < N_TOK) { noff = (size_t)n * 256 + h * 32; ok = true; }
            } else {
                if (rloc < NR) {
                    int wz = rloc / 49, tr2 = rloc % 49, wy = tr2 / 7, wx = tr2 % 7;
                    int nq = (zb * 7 + wz) * 784 + (yb * 7 + wy) * 28 + (xw * 7 + wx);
                    noff = (size_t)nq * 256 + 128 + h * 32; ok = true;
                }
            }
            if (ok) {
                const u16* lp = lepe + noff;
                u16* op = o + noff;
                op[fr]      = f2bf(o0[r] * inv_l[r] + bf2f(lp[fr]));
                op[16 + fr] = f2bf(o1[r] * inv_l[r] + bf2f(lp[16 + fr]));
            }
        }
        aq = aqn;
    }
}

// ---------------------------------------------------------------------------
extern "C" void kernel_launch(void* const* d_in, const int* in_sizes, int n_in,
                              void* d_out, int out_size, void* d_ws, size_t ws_size,
                              hipStream_t stream)
{
    const float* x       = (const float*)d_in[0];
    const float* lepe_w  = (const float*)d_in[4];
    const float* lepe_b  = (const float*)d_in[5];
    const float* lconv_w = (const float*)d_in[6];
    const float* lconv_b = (const float*)d_in[7];
    const float* sr_w    = (const float*)d_in[8];
    const float* sr_b    = (const float*)d_in[9];
    const float* norm_g  = (const float*)d_in[10];
    const float* norm_b  = (const float*)d_in[11];
    const float* q1_w    = (const float*)d_in[12];
    const float* kv1_w   = (const float*)d_in[13];
    const float* q2_w    = (const float*)d_in[14];
    const float* kv2_w   = (const float*)d_in[15];
    const float* proj_w  = (const float*)d_in[16];
    const float* proj_b  = (const float*)d_in[17];
    float* out = (float*)d_out;

    const size_t NC = (size_t)N_TOK * 256;

    float* partials = (float*)d_ws;                 // [32][343*256] fp32
    float* bias_all = partials + 32 * (NR * 256);   // [768]
    u16* xb     = (u16*)(bias_all + 768);           // bf16(x) [N,256]
    u16* xall   = xb + NC;                          // [N,768]: y|q1|q2|kv2
    u16* lepeb  = xall + (size_t)N_TOK * 768;       // [N,256]
    u16* colb   = lepeb + NC;                       // (o + lepe) [N,256]
    u16* x1b    = colb + NC;                        // [343,256]
    u16* kv1b   = x1b + NR * 256;                   // [343,256]
    u16* wb_comb = kv1b + NR * 256;                 // [768,256]
    u16* wb_k1  = wb_comb + 196608;                 // [256,256]
    u16* wb_p   = wb_k1 + 65536;                    // [256,256]
    u16* wsr_t  = wb_p + 65536;                     // [64][256,256]
    size_t need = (size_t)(32 * NR * 256 + 768) * 4 +
                  (NC + (size_t)N_TOK * 768 + 3 * NC + 2 * (size_t)NR * 256 +
                   196608 + 2 * 65536 + 4194304) * 2;
    if (ws_size < need) return;

    // 0a. weights -> bf16 (q pre-scaled incl. log2e), bias_all
    convert_w_kernel<<<dim3(321), 256, 0, stream>>>(
        lepe_w, q1_w, q2_w, kv2_w, kv1_w, proj_w, lepe_b,
        wb_comb, wb_k1, wb_p, bias_all);
    // 0b. sr_w -> [tap][co][ci] bf16
    convert_sr_kernel<<<dim3(256), 256, 0, stream>>>(sr_w, wsr_t);
    // 0c. x -> bf16
    convert_x_kernel<<<dim3(2744), 256, 0, stream>>>(x, xb);
    // 1. xall = xb @ [lepe|q1|q2|kv2]^T + bias_all  (172 x 12 n-tiles)
    gemm_lds<<<dim3(172 * 12), 256, 0, stream>>>(
        xb, wb_comb, bias_all, xall, N_TOK, 768, 0, 172 * 12, 12);
    // 2. lepe = depthwise conv(y)
    dwconv_kernel<<<dim3(343, 4), 256, 0, stream>>>(xall, lconv_w, lconv_b, lepeb);
    // 3. SR conv: tap-split GEMM into partials
    sr_gemm<<<dim3(3, 4, 32), 256, 0, stream>>>(xb, wsr_t, partials);
    // 4. x1 = gelu(layernorm(sum partials + sr_b))
    ln_gelu_kernel<<<dim3(NR), 256, 0, stream>>>(partials, sr_b, norm_g, norm_b, x1b);
    // 5. kv1 = x1 @ kv1_w^T
    gemm_lds<<<dim3(3 * 4), 256, 0, stream>>>(
        x1b, wb_k1, nullptr, kv1b, NR, 256, 0, 3 * 4, 4);
    // 6+7. both attention branches, output = o + lepe  (1016 blocks, 2 passes)
    attn_kernel<<<dim3(127, 4, 2), 256, 0, stream>>>(xall, kv1b, lepeb, colb);
    // 8. out = colb @ proj_w^T + proj_b  (fp32 out)
    gemm_lds<<<dim3(172 * 4), 256, 0, stream>>>(
        colb, wb_p, proj_b, out, N_TOK, 256, 1, 172 * 4, 4);
}

// Round 15
// 253.166 us; speedup vs baseline: 1.0321x; 1.0321x over previous
//
#include <hip/hip_runtime.h>

#define N_TOK 21952          // 28*28*28
#define NR    343            // 7*7*7
#define ATT_SCALE 0.17677669529663687f   // 32^-0.5
#define LOG2E 1.44269504088896340736f

typedef unsigned short u16;
typedef short  v8s __attribute__((ext_vector_type(8)));
typedef float  v4f __attribute__((ext_vector_type(4)));

__device__ __forceinline__ float bf2f(unsigned u) {
    return __builtin_bit_cast(float, u << 16);
}
__device__ __forceinline__ u16 f2bf(float f) {
    unsigned u = __builtin_bit_cast(unsigned, f);
    u += 0x7fffu + ((u >> 16) & 1u);
    return (u16)(u >> 16);
}

// CK-pattern global->LDS DMA (16B/lane).  LDS dest = wave-uniform base +
// lane*16 (m104); on gfx950 the low 32 bits of a flat LDS pointer ARE the
// LDS byte offset.
__device__ __forceinline__ void gload_lds16(const u16* g, u16* l) {
    __builtin_amdgcn_global_load_lds(
        (const __attribute__((address_space(1))) unsigned*)g,
        (__attribute__((address_space(3))) unsigned*)(unsigned)(uintptr_t)l,
        16, 0, 0);
}

// ---------------------------------------------------------------------------
// x fp32 -> bf16 (xb).  8 elems / thread, exact grid.
// ---------------------------------------------------------------------------
__global__ __launch_bounds__(256) void convert_x_kernel(
    const float* __restrict__ x, u16* __restrict__ xb)
{
    size_t i = ((size_t)blockIdx.x * 256 + threadIdx.x) * 8;   // exact: N*256
    float4 a0 = *(const float4*)(x + i);
    float4 a1 = *(const float4*)(x + i + 4);
    uint4 av;
    av.x = (unsigned)f2bf(a0.x) | ((unsigned)f2bf(a0.y) << 16);
    av.y = (unsigned)f2bf(a0.z) | ((unsigned)f2bf(a0.w) << 16);
    av.z = (unsigned)f2bf(a1.x) | ((unsigned)f2bf(a1.y) << 16);
    av.w = (unsigned)f2bf(a1.z) | ((unsigned)f2bf(a1.w) << 16);
    *(uint4*)(xb + i) = av;
}

// ---------------------------------------------------------------------------
// Weight conversion fp32->bf16.  q weights pre-scaled by ATT_SCALE*LOG2E so
// attention can use native exp2.
// ---------------------------------------------------------------------------
#define WSEG0 16384   // lepe  (65536/4)
#define WSEG1 24576   // +q1   (32768/4)
#define WSEG2 32768   // +q2
#define WSEG3 49152   // +kv2  (65536/4)
#define WSEG4 65536   // +k1
#define WSEG5 81920   // +proj
#define WSEG6 82112   // +bias (768/4)

__global__ __launch_bounds__(256) void convert_w_kernel(
    const float* __restrict__ wl,  const float* __restrict__ wq1,
    const float* __restrict__ wq2, const float* __restrict__ wk2,
    const float* __restrict__ wk1, const float* __restrict__ wp,
    const float* __restrict__ lepe_b,
    u16* wb_comb, u16* wb_k1, u16* wb_p, float* bias_all)
{
    int gid = blockIdx.x * 256 + threadIdx.x;
    if (gid >= WSEG6) return;
    if (gid >= WSEG5) {                      // bias_all
        int b = gid - WSEG5;
        float4 v;
        int i = b * 4;
        v.x = (i + 0 < 256) ? lepe_b[i + 0] : 0.f;
        v.y = (i + 1 < 256) ? lepe_b[i + 1] : 0.f;
        v.z = (i + 2 < 256) ? lepe_b[i + 2] : 0.f;
        v.w = (i + 3 < 256) ? lepe_b[i + 3] : 0.f;
        *(float4*)(bias_all + i) = v;
        return;
    }
    const float* s; u16* d; int l; float sc = 1.f;
    if      (gid < WSEG0) { s = wl;  d = wb_comb;           l = gid; }
    else if (gid < WSEG1) { s = wq1; d = wb_comb + 65536;   l = gid - WSEG0; sc = ATT_SCALE * LOG2E; }
    else if (gid < WSEG2) { s = wq2; d = wb_comb + 98304;   l = gid - WSEG1; sc = ATT_SCALE * LOG2E; }
    else if (gid < WSEG3) { s = wk2; d = wb_comb + 131072;  l = gid - WSEG2; }
    else if (gid < WSEG4) { s = wk1; d = wb_k1;             l = gid - WSEG3; }
    else                  { s = wp;  d = wb_p;              l = gid - WSEG4; }
    float4 v = *(const float4*)(s + (size_t)l * 4);
    *(ushort4*)(d + (size_t)l * 4) =
        make_ushort4(f2bf(v.x * sc), f2bf(v.y * sc), f2bf(v.z * sc), f2bf(v.w * sc));
}

// ---------------------------------------------------------------------------
// sr_w [co][ci][tap] fp32 -> wsr_t [tap][co][ci] bf16.
// ---------------------------------------------------------------------------
__global__ __launch_bounds__(256) void convert_sr_kernel(
    const float* __restrict__ wsr, u16* __restrict__ wt)
{
    int u  = blockIdx.x * 256 + threadIdx.x;   // 65536 = 256 co x 256 ci
    int co = u >> 8, ci = u & 255;
    const float* src = wsr + (size_t)co * 16384 + ci * 64;
#pragma unroll
    for (int t4 = 0; t4 < 16; t4++) {
        float4 v = *(const float4*)(src + t4 * 4);
        int t = t4 * 4;
        wt[(size_t)(t + 0) * 65536 + co * 256 + ci] = f2bf(v.x);
        wt[(size_t)(t + 1) * 65536 + co * 256 + ci] = f2bf(v.y);
        wt[(size_t)(t + 2) * 65536 + co * 256 + ci] = f2bf(v.z);
        wt[(size_t)(t + 3) * 65536 + co * 256 + ci] = f2bf(v.w);
    }
}

// ---------------------------------------------------------------------------
// m97-structure K=256 GEMM with global_load_lds staging (width 16):
//   out[M,ldout] = A @ W^T [+ bias]
// BM=128 x BN=64, BK=32, single-buffered linear LDS.
// mode: 0 = bf16 out (+bias), 1 = fp32 out (+bias, scalar stores)
// ---------------------------------------------------------------------------
__global__ __launch_bounds__(256, 4) void gemm_lds(
    const u16* __restrict__ A, const u16* __restrict__ W,
    const float* __restrict__ bias, void* __restrict__ outp,
    int M, int ldout, int mode, int nwg, int NT)
{
    __shared__ u16 smbuf[128 * 64];            // 16 KB; K-loop uses 12 KB
    u16* Asm = smbuf;                          // [128][32]
    u16* Bsm = smbuf + 128 * 32;               // [64][32]
    const int tid = threadIdx.x;

    // bijective XCD swizzle (m204)
    int bid = blockIdx.x;
    int q = nwg >> 3, r8 = nwg & 7;
    int xcd = bid & 7, idx = bid >> 3;
    int wgid = (xcd < r8 ? xcd * (q + 1) : r8 * (q + 1) + (xcd - r8) * q) + idx;
    const int m0 = (wgid / NT) * 128;
    const int n0 = (wgid % NT) * 64;

    const int wave = tid >> 6, lane = tid & 63;
    const int wm = (wave & 1) * 64, wn = (wave >> 1) * 32;
    const int fr = lane & 15, fq = lane >> 4;

    const int l4 = lane >> 2, lc = (lane & 3) * 8;
    int ra0 = m0 + wave * 32 + l4;  if (ra0 >= M) ra0 = M - 1;
    int ra1 = ra0 + 16;             if (ra1 >= M) ra1 = M - 1;
    const u16* gA0 = A + (size_t)ra0 * 256 + lc;
    const u16* gA1 = A + (size_t)ra1 * 256 + lc;
    const u16* gB  = W + (size_t)(n0 + wave * 16 + l4) * 256 + lc;
    u16* ldsA0 = Asm + (wave * 32) * 32;
    u16* ldsA1 = Asm + (wave * 32 + 16) * 32;
    u16* ldsB  = Bsm + (wave * 16) * 32;

    v4f acc[4][2];
#pragma unroll
    for (int i = 0; i < 4; i++)
#pragma unroll
        for (int j = 0; j < 2; j++) acc[i][j] = (v4f){0.f, 0.f, 0.f, 0.f};

    for (int kk = 0; kk < 256; kk += 32) {
        gload_lds16(gA0 + kk, ldsA0);
        gload_lds16(gA1 + kk, ldsA1);
        gload_lds16(gB  + kk, ldsB);
        __syncthreads();

        v8s af[4], bf[2];
#pragma unroll
        for (int i = 0; i < 4; i++)
            af[i] = *(const v8s*)(Asm + (wm + i * 16 + fr) * 32 + fq * 8);
#pragma unroll
        for (int j = 0; j < 2; j++)
            bf[j] = *(const v8s*)(Bsm + (wn + j * 16 + fr) * 32 + fq * 8);
#pragma unroll
        for (int i = 0; i < 4; i++)
#pragma unroll
            for (int j = 0; j < 2; j++)
                acc[i][j] = __builtin_amdgcn_mfma_f32_16x16x32_bf16(
                    af[i], bf[j], acc[i][j], 0, 0, 0);
        __syncthreads();
    }

    if (mode == 0) {
#pragma unroll
        for (int i = 0; i < 4; i++)
#pragma unroll
            for (int j = 0; j < 2; j++) {
                int col = wn + j * 16 + fr;
#pragma unroll
                for (int rr = 0; rr < 4; rr++) {
                    int row = wm + i * 16 + fq * 4 + rr;
                    float v = acc[i][j][rr];
                    if (bias) v += bias[n0 + col];
                    smbuf[row * 64 + col] = f2bf(v);
                }
            }
        __syncthreads();
#pragma unroll
        for (int i = 0; i < 4; i++) {
            int u = tid + i * 256;              // 0..1023
            int row = u >> 3, seg = (u & 7) * 8;
            if (m0 + row < M) {
                uint4 a = *(const uint4*)(smbuf + row * 64 + seg);
                *(uint4*)((u16*)outp + (size_t)(m0 + row) * ldout + n0 + seg) = a;
            }
        }
    } else {
        float* outf = (float*)outp;
#pragma unroll
        for (int i = 0; i < 4; i++)
#pragma unroll
            for (int j = 0; j < 2; j++) {
                int col = n0 + wn + j * 16 + fr;
#pragma unroll
                for (int rr = 0; rr < 4; rr++) {
                    int row = m0 + wm + i * 16 + fq * 4 + rr;
                    if (row >= M) continue;
                    float v = acc[i][j][rr];
                    if (bias) v += bias[col];
                    outf[(size_t)row * ldout + col] = v;
                }
            }
    }
}

// ---------------------------------------------------------------------------
// SR conv as tap-split GEMM, LOAD-early/WRITE-late double-buffered.
// ---------------------------------------------------------------------------
#define LDA 40   // padded LDS row stride (bf16 elems)

__global__ __launch_bounds__(256) void sr_gemm(
    const u16* __restrict__ xb, const u16* __restrict__ Wt,
    float* __restrict__ partials)
{
    __shared__ u16 Asm[2][128 * LDA];
    __shared__ u16 Bsm[2][64 * LDA];
    const int tid = threadIdx.x;
    const int m0 = blockIdx.x * 128;   // p tile
    const int n0 = blockIdx.y * 64;    // co tile
    const int z  = blockIdx.z;         // taps 2z, 2z+1
    const int wave = tid >> 6, lane = tid & 63;
    const int wm = (wave & 1) * 64, wn = (wave >> 1) * 32;
    const int fr = lane & 15, fq = lane >> 4;

    const int r0 = tid >> 2;
    const int r1 = r0 + 64;
    const int seg = (tid & 3) * 8;
    const int p0 = m0 + r0, p1 = m0 + r1;
    const int pz0 = p0 / 49, pr0 = p0 % 49, py0 = pr0 / 7, px0 = pr0 % 7;
    const int pz1 = p1 / 49, pr1 = p1 % 49, py1 = pr1 / 7, px1 = pr1 % 7;
    const int nb0 = pz0 * 4 * 784 + py0 * 4 * 28 + px0 * 4;
    const int nb1 = pz1 * 4 * 784 + py1 * 4 * 28 + px1 * 4;

    uint4 rv0, rv1, rbv;
    const uint4 Z = make_uint4(0, 0, 0, 0);

    auto G_LOAD = [&](int it) {
        int tap = z * 2 + (it >> 3);
        int ci0 = (it & 7) * 32;
        int kz = tap >> 4, ky = (tap >> 2) & 3, kx = tap & 3;
        int koff = kz * 784 + ky * 28 + kx;
        rv0 = (p0 < NR) ? *(const uint4*)(xb + (size_t)(nb0 + koff) * 256 + ci0 + seg) : Z;
        rv1 = (p1 < NR) ? *(const uint4*)(xb + (size_t)(nb1 + koff) * 256 + ci0 + seg) : Z;
        rbv = *(const uint4*)(Wt + (size_t)tap * 65536 + (size_t)(n0 + r0) * 256 + ci0 + seg);
    };
    auto L_WRITE = [&](int buf) {
        *(uint4*)(Asm[buf] + r0 * LDA + seg) = rv0;
        *(uint4*)(Asm[buf] + r1 * LDA + seg) = rv1;
        *(uint4*)(Bsm[buf] + r0 * LDA + seg) = rbv;
    };

    v4f acc[4][2];
#pragma unroll
    for (int i = 0; i < 4; i++)
#pragma unroll
        for (int j = 0; j < 2; j++) acc[i][j] = (v4f){0.f, 0.f, 0.f, 0.f};

    G_LOAD(0);
    L_WRITE(0);
    __syncthreads();

    int cur = 0;
    for (int it = 0; it < 16; it++) {
        if (it + 1 < 16) G_LOAD(it + 1);
        {
            v8s af[4], bfr[2];
#pragma unroll
            for (int i = 0; i < 4; i++)
                af[i] = *(const v8s*)(Asm[cur] + (wm + i * 16 + fr) * LDA + fq * 8);
#pragma unroll
            for (int j = 0; j < 2; j++)
                bfr[j] = *(const v8s*)(Bsm[cur] + (wn + j * 16 + fr) * LDA + fq * 8);
#pragma unroll
            for (int i = 0; i < 4; i++)
#pragma unroll
                for (int j = 0; j < 2; j++)
                    acc[i][j] = __builtin_amdgcn_mfma_f32_16x16x32_bf16(
                        af[i], bfr[j], acc[i][j], 0, 0, 0);
        }
        if (it + 1 < 16) L_WRITE(cur ^ 1);
        __syncthreads();
        cur ^= 1;
    }

    float* dst = partials + (size_t)z * (NR * 256);
#pragma unroll
    for (int i = 0; i < 4; i++) {
#pragma unroll
        for (int j = 0; j < 2; j++) {
            int col = n0 + wn + j * 16 + fr;
#pragma unroll
            for (int r = 0; r < 4; r++) {
                int row = m0 + wm + i * 16 + fq * 4 + r;
                if (row < NR) dst[(size_t)row * 256 + col] = acc[i][j][r];
            }
        }
    }
}

// ---------------------------------------------------------------------------
// Reduce 32 partials + sr bias, LayerNorm (C=256) + exact GELU -> bf16.
// ---------------------------------------------------------------------------
__global__ __launch_bounds__(256) void ln_gelu_kernel(
    const float* __restrict__ partials, const float* __restrict__ srb,
    const float* __restrict__ g, const float* __restrict__ b,
    u16* __restrict__ out)
{
    int row = blockIdx.x, c = threadIdx.x;
    float v = srb[c];
#pragma unroll
    for (int s = 0; s < 32; s++)
        v += partials[(size_t)s * (NR * 256) + row * 256 + c];
    float s1 = v, s2 = v * v;
#pragma unroll
    for (int off = 1; off < 64; off <<= 1) {
        s1 += __shfl_xor(s1, off);
        s2 += __shfl_xor(s2, off);
    }
    __shared__ float ws[4], ws2[4];
    int wave = c >> 6, lane = c & 63;
    if (lane == 0) { ws[wave] = s1; ws2[wave] = s2; }
    __syncthreads();
    float mean = (ws[0] + ws[1] + ws[2] + ws[3]) * (1.f / 256.f);
    float m2   = (ws2[0] + ws2[1] + ws2[2] + ws2[3]) * (1.f / 256.f);
    float var  = m2 - mean * mean;
    float xn = (v - mean) * rsqrtf(var + 1e-5f) * g[c] + b[c];
    out[row * 256 + c] = f2bf(0.5f * xn * (1.f + erff(xn * 0.70710678118654752f)));
}

// ---------------------------------------------------------------------------
// Depthwise 3x3x3 SAME conv, LDS-tiled.  y = xall cols 0..255 (row stride 768).
// ---------------------------------------------------------------------------
__global__ __launch_bounds__(256) void dwconv_kernel(
    const u16* __restrict__ xall, const float* __restrict__ w,
    const float* __restrict__ bias, u16* __restrict__ out)
{
    __shared__ float sm[216 * 64];
    __shared__ float sw[64 * 27];
    const int tid = threadIdx.x;
    const int t  = blockIdx.x;
    const int g  = blockIdx.y;
    const int tz = t / 49, tr = t % 49, ty = tr / 7, tx = tr % 7;

    for (int u = tid; u < 64 * 27; u += 256) sw[u] = w[g * 64 * 27 + u];

    for (int u = tid; u < 216 * 8; u += 256) {
        int r = u >> 3, c8 = (u & 7) * 8;
        int vz = tz * 4 - 1 + r / 36;
        int rem = r % 36;
        int vy = ty * 4 - 1 + rem / 6;
        int vx = tx * 4 - 1 + rem % 6;
        float f[8];
        if ((unsigned)vz < 28u && (unsigned)vy < 28u && (unsigned)vx < 28u) {
            int n = vz * 784 + vy * 28 + vx;
            uint4 raw = *(const uint4*)(xall + (size_t)n * 768 + g * 64 + c8);
            f[0] = bf2f(raw.x & 0xffffu); f[1] = bf2f(raw.x >> 16);
            f[2] = bf2f(raw.y & 0xffffu); f[3] = bf2f(raw.y >> 16);
            f[4] = bf2f(raw.z & 0xffffu); f[5] = bf2f(raw.z >> 16);
            f[6] = bf2f(raw.w & 0xffffu); f[7] = bf2f(raw.w >> 16);
        } else {
#pragma unroll
            for (int i = 0; i < 8; i++) f[i] = 0.f;
        }
        float* dst = &sm[r * 64 + c8];
        *(float4*)dst       = make_float4(f[0], f[1], f[2], f[3]);
        *(float4*)(dst + 4) = make_float4(f[4], f[5], f[6], f[7]);
    }
    __syncthreads();

    const int c  = tid & 63;
    const int ch = g * 64 + c;
    float wreg[27];
#pragma unroll
    for (int j = 0; j < 27; j++) wreg[j] = sw[c * 27 + j];
    const float bc = bias[ch];

    const int vbase = (tid >> 6) * 16;
    for (int v = vbase; v < vbase + 16; v++) {
        int vz = v >> 4, vy = (v >> 2) & 3, vx = v & 3;
        float a = bc;
#pragma unroll
        for (int dz = 0; dz < 3; dz++)
#pragma unroll
            for (int dy = 0; dy < 3; dy++)
#pragma unroll
                for (int dx = 0; dx < 3; dx++)
                    a = fmaf(sm[((vz + dz) * 36 + (vy + dy) * 6 + (vx + dx)) * 64 + c],
                             wreg[dz * 9 + dy * 3 + dx], a);
        int n = (tz * 4 + vz) * 784 + (ty * 4 + vy) * 28 + (tx * 4 + vx);
        out[(size_t)n * 256 + ch] = f2bf(a);
    }
}

// ===========================================================================
// Unified MFMA attention + fused "+lepe" epilogue.
// ROUND 15: 512-thread blocks (8 waves), grid (127,4) = 508 blocks.
// Fixes r9's failed merge: per-wave chain stays <=3 m-tiles (mt += 8), but
//  - 2 blocks/CU x 8 waves = 16 waves/CU (was 8): doubled TLP for a
//    latency-bound kernel (3 scheduling levers all null -> TLP is binding);
//  - K/V staged ONCE per (bx,h) (was twice): FETCH 45 -> ~23 MB;
//  - 508 blocks <= 512 co-resident slots: single dispatch pass.
// Per-wave code identical to r14 (exp2, tree reductions, P-dbuf, setprio).
// ===========================================================================
#define KP  40    // K LDS row stride (bf16)
#define VTP 360   // V^T LDS row stride (bf16)
#define PP  40    // P LDS row stride (bf16)

__global__ __launch_bounds__(512) void attn_kernel(
    const u16* __restrict__ xall, const u16* __restrict__ kv1,
    const u16* __restrict__ lepe, u16* __restrict__ o)
{
    __shared__ u16 Ks[352 * KP];
    __shared__ u16 VTs[32 * VTP];
    __shared__ u16 Ps[8 * 2 * 16 * PP];      // 2 P buffers per wave, 8 waves
    const int tid = threadIdx.x;
    const int bx = blockIdx.x;         // 0..126  (window / q-tile id)
    const int h  = blockIdx.y;         // head
    const bool br1 = bx < 63;
    const int qbase = bx * 352;                    // branch-1 only
    const int wi = bx - 63;                        // branch-2 only
    const int zb = (wi >> 4) & 3, yb = (wi >> 2) & 3, xw = wi & 3;
    const int wave = tid >> 6, lane = tid & 63;
    const int fr = lane & 15, fq = lane >> 4;

    for (int u = tid; u < 352 * 4; u += 512) {
        int r = u >> 2, seg = u & 3;
        uint4 kq = make_uint4(0, 0, 0, 0), vq = make_uint4(0, 0, 0, 0);
        if (r < NR) {
            const u16* kb;
            if (br1) {
                kb = kv1 + (size_t)r * 256 + h * 32;
            } else {
                int mz = r / 49, mr = r % 49, my = mr / 7, mx = mr % 7;
                int nk = (zb * 7 + mz) * 784 + (yb * 7 + my) * 28 + (xw * 7 + mx);
                kb = xall + (size_t)nk * 768 + 512 + h * 32;
            }
            kq = *(const uint4*)(kb + seg * 8);
            vq = *(const uint4*)(kb + 128 + seg * 8);
        }
        *(uint4*)(Ks + r * KP + seg * 8) = kq;
        int d0 = seg * 8;
        VTs[(d0 + 0) * VTP + r] = (u16)(vq.x & 0xffffu);
        VTs[(d0 + 1) * VTP + r] = (u16)(vq.x >> 16);
        VTs[(d0 + 2) * VTP + r] = (u16)(vq.y & 0xffffu);
        VTs[(d0 + 3) * VTP + r] = (u16)(vq.y >> 16);
        VTs[(d0 + 4) * VTP + r] = (u16)(vq.z & 0xffffu);
        VTs[(d0 + 5) * VTP + r] = (u16)(vq.z >> 16);
        VTs[(d0 + 6) * VTP + r] = (u16)(vq.w & 0xffffu);
        VTs[(d0 + 7) * VTP + r] = (u16)(vq.w >> 16);
    }
    __syncthreads();

    auto load_aq = [&](int mt) -> v8s {
        v8s a = {0, 0, 0, 0, 0, 0, 0, 0};
        if (br1) {
            int qrow = qbase + mt * 16 + fr;
            if (qrow < N_TOK)
                a = *(const v8s*)(xall + (size_t)qrow * 768 + 256 + h * 32 + fq * 8);
        } else {
            int tw = mt * 16 + fr;
            if (tw < NR) {
                int wz = tw / 49, tr2 = tw % 49, wy = tr2 / 7, wx = tr2 % 7;
                int nq = (zb * 7 + wz) * 784 + (yb * 7 + wy) * 28 + (xw * 7 + wx);
                a = *(const v8s*)(xall + (size_t)nq * 768 + 384 + h * 32 + fq * 8);
            }
        }
        return a;
    };

    u16* Pw0 = Ps + wave * 2 * 16 * PP;
    u16* Pw1 = Pw0 + 16 * PP;
    v8s aq = load_aq(wave);
    for (int mt = wave; mt < 22; mt += 8) {
        v4f s[22];
        __builtin_amdgcn_s_setprio(1);
#pragma unroll
        for (int t = 0; t < 22; t++) {
            v8s bk = *(const v8s*)(Ks + (t * 16 + fr) * KP + fq * 8);
            s[t] = __builtin_amdgcn_mfma_f32_16x16x32_bf16(
                aq, bk, (v4f){0.f, 0.f, 0.f, 0.f}, 0, 0, 0);
        }
        __builtin_amdgcn_s_setprio(0);
        // prefetch next m-tile's q fragment: latency hides under softmax+PV
        v8s aqn = {0, 0, 0, 0, 0, 0, 0, 0};
        if (mt + 8 < 22) aqn = load_aq(mt + 8);

        if (fr >= 7) {
#pragma unroll
            for (int r = 0; r < 4; r++) s[21][r] = -1e30f;
        }

        float inv_l[4];
#pragma unroll
        for (int r = 0; r < 4; r++) {
            // tree max (depth ~5)
            float a[11];
#pragma unroll
            for (int t = 0; t < 11; t++) a[t] = fmaxf(s[2 * t][r], s[2 * t + 1][r]);
#pragma unroll
            for (int t = 0; t < 5; t++) a[t] = fmaxf(a[t], a[t + 5]);
            float m = fmaxf(fmaxf(fmaxf(a[0], a[1]), fmaxf(a[2], a[3])),
                            fmaxf(a[4], a[10]));
#pragma unroll
            for (int off = 1; off < 16; off <<= 1) m = fmaxf(m, __shfl_xor(m, off));
            // native exp2 (scores pre-scaled by log2e) + tree sum
#pragma unroll
            for (int t = 0; t < 22; t++) {
                v4f sv = s[t];
                sv[r] = __builtin_amdgcn_exp2f(sv[r] - m);
                s[t] = sv;
            }
            float e[11];
#pragma unroll
            for (int t = 0; t < 11; t++) e[t] = s[t][r] + s[t + 11][r];
#pragma unroll
            for (int t = 0; t < 5; t++) e[t] += e[t + 6];
            float l = ((e[0] + e[1]) + (e[2] + e[3])) + (e[4] + e[5]);
#pragma unroll
            for (int off = 1; off < 16; off <<= 1) l += __shfl_xor(l, off);
            inv_l[r] = 1.f / l;
        }

        // --- PV with double-buffered P ---
#pragma unroll
        for (int tt = 0; tt < 2; tt++)
#pragma unroll
            for (int r = 0; r < 4; r++)
                Pw0[(fq * 4 + r) * PP + tt * 16 + fr] = f2bf(s[tt][r]);

        v4f o0 = {0.f, 0.f, 0.f, 0.f}, o1 = {0.f, 0.f, 0.f, 0.f};
#pragma unroll
        for (int kt = 0; kt < 11; kt++) {
            u16* curb = (kt & 1) ? Pw1 : Pw0;
            u16* nxtb = (kt & 1) ? Pw0 : Pw1;
            __asm__ volatile("s_waitcnt lgkmcnt(0)" ::: "memory");
            v8s ap  = *(const v8s*)(curb + fr * PP + fq * 8);
            v8s bv0 = *(const v8s*)(VTs + fr * VTP + kt * 32 + fq * 8);
            v8s bv1 = *(const v8s*)(VTs + (16 + fr) * VTP + kt * 32 + fq * 8);
            if (kt + 1 < 11) {
#pragma unroll
                for (int tt = 0; tt < 2; tt++) {
                    int t = (kt + 1) * 2 + tt;
#pragma unroll
                    for (int r = 0; r < 4; r++)
                        nxtb[(fq * 4 + r) * PP + tt * 16 + fr] = f2bf(s[t][r]);
                }
            }
            __builtin_amdgcn_s_setprio(1);
            o0 = __builtin_amdgcn_mfma_f32_16x16x32_bf16(ap, bv0, o0, 0, 0, 0);
            o1 = __builtin_amdgcn_mfma_f32_16x16x32_bf16(ap, bv1, o1, 0, 0, 0);
            __builtin_amdgcn_s_setprio(0);
        }

#pragma unroll
        for (int r = 0; r < 4; r++) {
            int rloc = mt * 16 + fq * 4 + r;
            size_t noff = 0; bool ok = false;
            if (br1) {
                int n = qbase + rloc;
                if (n < N_TOK) { noff = (size_t)n * 256 + h * 32; ok = true; }
            } else {
                if (rloc < NR) {
                    int wz = rloc / 49, tr2 = rloc % 49, wy = tr2 / 7, wx = tr2 % 7;
                    int nq = (zb * 7 + wz) * 784 + (yb * 7 + wy) * 28 + (xw * 7 + wx);
                    noff = (size_t)nq * 256 + 128 + h * 32; ok = true;
                }
            }
            if (ok) {
                const u16* lp = lepe + noff;
                u16* op = o + noff;
                op[fr]      = f2bf(o0[r] * inv_l[r] + bf2f(lp[fr]));
                op[16 + fr] = f2bf(o1[r] * inv_l[r] + bf2f(lp[16 + fr]));
            }
        }
        aq = aqn;
    }
}

// ---------------------------------------------------------------------------
extern "C" void kernel_launch(void* const* d_in, const int* in_sizes, int n_in,
                              void* d_out, int out_size, void* d_ws, size_t ws_size,
                              hipStream_t stream)
{
    const float* x       = (const float*)d_in[0];
    const float* lepe_w  = (const float*)d_in[4];
    const float* lepe_b  = (const float*)d_in[5];
    const float* lconv_w = (const float*)d_in[6];
    const float* lconv_b = (const float*)d_in[7];
    const float* sr_w    = (const float*)d_in[8];
    const float* sr_b    = (const float*)d_in[9];
    const float* norm_g  = (const float*)d_in[10];
    const float* norm_b  = (const float*)d_in[11];
    const float* q1_w    = (const float*)d_in[12];
    const float* kv1_w   = (const float*)d_in[13];
    const float* q2_w    = (const float*)d_in[14];
    const float* kv2_w   = (const float*)d_in[15];
    const float* proj_w  = (const float*)d_in[16];
    const float* proj_b  = (const float*)d_in[17];
    float* out = (float*)d_out;

    const size_t NC = (size_t)N_TOK * 256;

    float* partials = (float*)d_ws;                 // [32][343*256] fp32
    float* bias_all = partials + 32 * (NR * 256);   // [768]
    u16* xb     = (u16*)(bias_all + 768);           // bf16(x) [N,256]
    u16* xall   = xb + NC;                          // [N,768]: y|q1|q2|kv2
    u16* lepeb  = xall + (size_t)N_TOK * 768;       // [N,256]
    u16* colb   = lepeb + NC;                       // (o + lepe) [N,256]
    u16* x1b    = colb + NC;                        // [343,256]
    u16* kv1b   = x1b + NR * 256;                   // [343,256]
    u16* wb_comb = kv1b + NR * 256;                 // [768,256]
    u16* wb_k1  = wb_comb + 196608;                 // [256,256]
    u16* wb_p   = wb_k1 + 65536;                    // [256,256]
    u16* wsr_t  = wb_p + 65536;                     // [64][256,256]
    size_t need = (size_t)(32 * NR * 256 + 768) * 4 +
                  (NC + (size_t)N_TOK * 768 + 3 * NC + 2 * (size_t)NR * 256 +
                   196608 + 2 * 65536 + 4194304) * 2;
    if (ws_size < need) return;

    // 0a. weights -> bf16 (q pre-scaled incl. log2e), bias_all
    convert_w_kernel<<<dim3(321), 256, 0, stream>>>(
        lepe_w, q1_w, q2_w, kv2_w, kv1_w, proj_w, lepe_b,
        wb_comb, wb_k1, wb_p, bias_all);
    // 0b. sr_w -> [tap][co][ci] bf16
    convert_sr_kernel<<<dim3(256), 256, 0, stream>>>(sr_w, wsr_t);
    // 0c. x -> bf16
    convert_x_kernel<<<dim3(2744), 256, 0, stream>>>(x, xb);
    // 1. xall = xb @ [lepe|q1|q2|kv2]^T + bias_all  (172 x 12 n-tiles)
    gemm_lds<<<dim3(172 * 12), 256, 0, stream>>>(
        xb, wb_comb, bias_all, xall, N_TOK, 768, 0, 172 * 12, 12);
    // 2. lepe = depthwise conv(y)
    dwconv_kernel<<<dim3(343, 4), 256, 0, stream>>>(xall, lconv_w, lconv_b, lepeb);
    // 3. SR conv: tap-split GEMM into partials
    sr_gemm<<<dim3(3, 4, 32), 256, 0, stream>>>(xb, wsr_t, partials);
    // 4. x1 = gelu(layernorm(sum partials + sr_b))
    ln_gelu_kernel<<<dim3(NR), 256, 0, stream>>>(partials, sr_b, norm_g, norm_b, x1b);
    // 5. kv1 = x1 @ kv1_w^T
    gemm_lds<<<dim3(3 * 4), 256, 0, stream>>>(
        x1b, wb_k1, nullptr, kv1b, NR, 256, 0, 3 * 4, 4);
    // 6+7. both attention branches, output = o + lepe  (508 blocks x 512 thr)
    attn_kernel<<<dim3(127, 4), 512, 0, stream>>>(xall, kv1b, lepeb, colb);
    // 8. out = colb @ proj_w^T + proj_b  (fp32 out)
    gemm_lds<<<dim3(172 * 4), 256, 0, stream>>>(
        colb, wb_p, proj_b, out, N_TOK, 256, 1, 172 * 4, 4);
}